// Round 3
// baseline (753.672 us; speedup 1.0000x reference)
//
#include <hip/hip_runtime.h>
#include <hip/hip_bf16.h>

typedef unsigned short u16;
typedef __attribute__((ext_vector_type(8))) short bf16x8;
typedef __attribute__((ext_vector_type(4))) float f32x4;

#define DEVINL __device__ __forceinline__

DEVINL u16 f2b(float f) {
    __hip_bfloat16 h = __float2bfloat16(f);
    return __builtin_bit_cast(u16, h);
}
DEVINL float b2f(u16 u) {
    unsigned int x = ((unsigned int)u) << 16;
    return __builtin_bit_cast(float, x);
}
DEVINL int iabs(int x) { return x < 0 ? -x : x; }
DEVINL f32x4 MFMA(bf16x8 a, bf16x8 b, f32x4 c) {
    return __builtin_amdgcn_mfma_f32_16x16x32_bf16(a, b, c, 0, 0, 0);
}

#define GL2LDS(g, s)                                                                     \
    __builtin_amdgcn_global_load_lds(                                                    \
        (const __attribute__((address_space(1))) unsigned int*)(g),                      \
        (__attribute__((address_space(3))) unsigned int*)(s), 16, 0, 0)

#define BAR __builtin_amdgcn_s_barrier()
#define LGKM0                                                                            \
    asm volatile("s_waitcnt lgkmcnt(0)" ::: "memory");                                   \
    __builtin_amdgcn_sched_barrier(0)
#define VMCNT(n) asm volatile("s_waitcnt vmcnt(" #n ")" ::: "memory")

// ---------------------------------------------------------------------------
// Weight convert + transpose: w[k][n] f32 -> wt[n][k] bf16
// ---------------------------------------------------------------------------
__global__ __launch_bounds__(256) void wconv_kernel(const float* __restrict__ wq,
                                                    const float* __restrict__ wk,
                                                    const float* __restrict__ wv,
                                                    const float* __restrict__ wo,
                                                    u16* __restrict__ wqkvt,
                                                    u16* __restrict__ wot) {
    __shared__ float tile[32][33];
    int z = blockIdx.z;
    const float* src = (z == 0) ? wq : (z == 1) ? wk : (z == 2) ? wv : wo;
    int n0 = blockIdx.x * 32, k0 = blockIdx.y * 32;
    int r0 = threadIdx.x >> 5, c = threadIdx.x & 31;
#pragma unroll
    for (int i = 0; i < 4; i++) {
        int r = r0 + i * 8;
        tile[r][c] = src[(size_t)(k0 + r) * 1024 + n0 + c];
    }
    __syncthreads();
    u16* dst = (z < 3) ? (wqkvt + (size_t)z * 1024 * 1024) : wot;
#pragma unroll
    for (int i = 0; i < 4; i++) {
        int r = r0 + i * 8;
        dst[(size_t)(n0 + r) * 1024 + k0 + c] = f2b(tile[c][r]);
    }
}

// ---------------------------------------------------------------------------
// LayerNorm: one wave per 1024-elem row, output bf16
// ---------------------------------------------------------------------------
__global__ __launch_bounds__(256) void ln_kernel(const float* __restrict__ x,
                                                 const float* __restrict__ gamma,
                                                 const float* __restrict__ beta,
                                                 u16* __restrict__ h) {
    int w = threadIdx.x >> 6, l = threadIdx.x & 63;
    size_t row = (size_t)blockIdx.x * 4 + w;
    const float4* xr = (const float4*)(x + row * 1024);
    float4 v[4];
    float s = 0.f, sq = 0.f;
#pragma unroll
    for (int i = 0; i < 4; i++) {
        v[i] = xr[l + i * 64];
        s += v[i].x + v[i].y + v[i].z + v[i].w;
        sq += v[i].x * v[i].x + v[i].y * v[i].y + v[i].z * v[i].z + v[i].w * v[i].w;
    }
#pragma unroll
    for (int off = 1; off < 64; off <<= 1) {
        s += __shfl_xor(s, off);
        sq += __shfl_xor(sq, off);
    }
    float mu = s * (1.f / 1024.f);
    float var = sq * (1.f / 1024.f) - mu * mu;
    float rstd = rsqrtf(var + 1e-5f);
    const float4* g4 = (const float4*)gamma;
    const float4* b4 = (const float4*)beta;
#pragma unroll
    for (int i = 0; i < 4; i++) {
        float4 g = g4[l + i * 64], b = b4[l + i * 64];
        float y0 = (v[i].x - mu) * rstd * g.x + b.x;
        float y1 = (v[i].y - mu) * rstd * g.y + b.y;
        float y2 = (v[i].z - mu) * rstd * g.z + b.z;
        float y3 = (v[i].w - mu) * rstd * g.w + b.w;
        unsigned int lo = (unsigned int)f2b(y0) | ((unsigned int)f2b(y1) << 16);
        unsigned int hi = (unsigned int)f2b(y2) | ((unsigned int)f2b(y3) << 16);
        uint2 pk;
        pk.x = lo;
        pk.y = hi;
        *(uint2*)(h + row * 1024 + (size_t)(l + i * 64) * 4) = pk;
    }
}

// ---------------------------------------------------------------------------
// GEMM 256x256 tile, BK=64, 512 threads (2M x 4N waves, each 128x64 output).
// Deep pipeline: per operand a ring of 4 k-half slabs (256 rows x 32k = 16KB,
// 64B rows, swizzle byte ^= ((row>>1)&3)<<4). Stage 1 half per phase
// (2 global_load_lds), consume 1.75 tiles later; ONE s_waitcnt vmcnt(6) per
// K-tile (3 halves in flight, never 0); raw s_barrier (no compiler drain).
// Phase p in tile T:  p1: read A-ks0(8)+B-ks0-qn0(2), stage B-kh1(T+1)
//                     p2: read B-ks0-qn1(2),          stage A-kh0(T+2)
//                     p3: read A-ks1(8)+B-ks1-qn0(2), stage B-kh0(T+2)
//                     p4: read B-ks1-qn1(2),          stage A-kh1(T+2), vmcnt(6)
// Hazard ledger: in-flight loads during tile T only target slots
// {(2T+2)&3,(2T+3)&3}, disjoint from T's read slots {(2T)&3,(2T+1)&3}; all
// slab overwrites barrier-separated from last ds_read; all ds_reads covered by
// a prior vmcnt(6)+barrier checkpoint.
// ---------------------------------------------------------------------------
template <int OUT_BF16, int RESID>
__global__ __launch_bounds__(512, 2) void gemm8(const u16* __restrict__ A,
                                                const u16* __restrict__ Bt,
                                                void* __restrict__ Cv,
                                                const u16* __restrict__ resid,
                                                int lda, int ldc) {
    __shared__ u16 smem[65536];  // 128KB: A slots [0,64K), B slots [64K,128K)
    char* sbase = (char*)smem;
    int t = threadIdx.x;

    // XCD-chunked swizzle (nwg % 8 == 0), supergroups of 4 bn per bm sweep.
    int nwg = gridDim.x;
    int cpx = nwg >> 3;
    int wg = ((int)blockIdx.x & 7) * cpx + ((int)blockIdx.x >> 3);
    int sn = wg / 896;
    int rem = wg - sn * 896;
    int bm = rem >> 2;
    int bn = sn * 4 + (rem & 3);

    // staging addresses: thread t covers slab byte chunk*8192 + t*16;
    // row = chunk*128 + (p16>>6), pcol = p16&63; logical col = pcol ^ swz(row)
    size_t ldaB = (size_t)lda * 2;
    int p16 = t * 16;
    int sr = p16 >> 6;                                 // 0..127
    int scb = (p16 & 63) ^ (((p16 >> 7) & 3) << 4);    // inverse-swizzled col byte
    const char* aB = (const char*)A + ((size_t)(bm * 256) + sr) * ldaB + scb;
    const char* bB = (const char*)Bt + ((size_t)(bn * 256) + sr) * 2048 + scb;
    const size_t aC = ldaB * 128;      // chunk 1 row offset
    const size_t bC = (size_t)2048 * 128;

    int l = t & 63, w = t >> 6;
    int wm = w >> 2, wn = w & 3, g = l >> 4, lr = l & 15;
    // frag byte offset within slab: (base16 + lr)*64 + (g*16 ^ ((lr>>1)&3)<<4)
    int fo = lr * 64 + ((g * 16) ^ (((lr >> 1) & 3) << 4));

    f32x4 acc[8][4];
#pragma unroll
    for (int m = 0; m < 8; m++)
#pragma unroll
        for (int n = 0; n < 4; n++) acc[m][n] = {0.f, 0.f, 0.f, 0.f};

// stage half H (= 2*tile + kh) of operand A/B into its ring slot
#define STA(H)                                                                           \
    do {                                                                                 \
        size_t ko = (size_t)(((H) >> 1) * 128 + ((H) & 1) * 64);                         \
        char* d = sbase + ((H) & 3) * 16384 + p16;                                       \
        GL2LDS(aB + ko, d);                                                              \
        GL2LDS(aB + aC + ko, d + 8192);                                                  \
    } while (0)
#define STB(H)                                                                           \
    do {                                                                                 \
        size_t ko = (size_t)(((H) >> 1) * 128 + ((H) & 1) * 64);                         \
        char* d = sbase + 65536 + ((H) & 3) * 16384 + p16;                               \
        GL2LDS(bB + ko, d);                                                              \
        GL2LDS(bB + bC + ko, d + 8192);                                                  \
    } while (0)

    // prologue: tile0 fully + tile1 first 3 halves (7 halves, 14 loads)
    STA(0); STB(0); STA(1); STB(1); STA(2); STB(2); STA(3);
    VMCNT(6);  // tile0's 4 halves landed; 3 of tile1 may be in flight
    BAR;

#pragma unroll 1
    for (int T = 0; T < 16; ++T) {
        const char* A0 = sbase + ((2 * T) & 3) * 16384;
        const char* A1 = sbase + ((2 * T + 1) & 3) * 16384;
        const char* B0 = sbase + 65536 + ((2 * T) & 3) * 16384;
        const char* B1 = sbase + 65536 + ((2 * T + 1) & 3) * 16384;
        bf16x8 af[2][4], b0[2], b1[2];

        // ---- p1: A ks0 (8 reads) + B ks0 qn0 (2); stage B-kh1(T+1) ----
#pragma unroll
        for (int qm = 0; qm < 2; qm++)
#pragma unroll
            for (int m = 0; m < 4; m++)
                af[qm][m] = *(const bf16x8*)(A0 + (wm * 128 + qm * 64 + m * 16) * 64 + fo);
#pragma unroll
        for (int n = 0; n < 2; n++)
            b0[n] = *(const bf16x8*)(B0 + (wn * 64 + n * 16) * 64 + fo);
        if (T < 15) STB(2 * (T + 1) + 1);
        BAR;
        LGKM0;
        __builtin_amdgcn_s_setprio(1);
#pragma unroll
        for (int qm = 0; qm < 2; qm++)
#pragma unroll
            for (int m = 0; m < 4; m++)
#pragma unroll
                for (int n = 0; n < 2; n++)
                    acc[qm * 4 + m][n] = MFMA(af[qm][m], b0[n], acc[qm * 4 + m][n]);
        __builtin_amdgcn_s_setprio(0);
        BAR;

        // ---- p2: B ks0 qn1 (2 reads); stage A-kh0(T+2) ----
#pragma unroll
        for (int n = 0; n < 2; n++)
            b1[n] = *(const bf16x8*)(B0 + (wn * 64 + 32 + n * 16) * 64 + fo);
        if (T < 14) STA(2 * (T + 2));
        BAR;
        LGKM0;
        __builtin_amdgcn_s_setprio(1);
#pragma unroll
        for (int qm = 0; qm < 2; qm++)
#pragma unroll
            for (int m = 0; m < 4; m++)
#pragma unroll
                for (int n = 0; n < 2; n++)
                    acc[qm * 4 + m][2 + n] = MFMA(af[qm][m], b1[n], acc[qm * 4 + m][2 + n]);
        __builtin_amdgcn_s_setprio(0);
        BAR;

        // ---- p3: A ks1 (8 reads) + B ks1 qn0 (2); stage B-kh0(T+2) ----
#pragma unroll
        for (int qm = 0; qm < 2; qm++)
#pragma unroll
            for (int m = 0; m < 4; m++)
                af[qm][m] = *(const bf16x8*)(A1 + (wm * 128 + qm * 64 + m * 16) * 64 + fo);
#pragma unroll
        for (int n = 0; n < 2; n++)
            b0[n] = *(const bf16x8*)(B1 + (wn * 64 + n * 16) * 64 + fo);
        if (T < 14) STB(2 * (T + 2));
        BAR;
        LGKM0;
        __builtin_amdgcn_s_setprio(1);
#pragma unroll
        for (int qm = 0; qm < 2; qm++)
#pragma unroll
            for (int m = 0; m < 4; m++)
#pragma unroll
                for (int n = 0; n < 2; n++)
                    acc[qm * 4 + m][n] = MFMA(af[qm][m], b0[n], acc[qm * 4 + m][n]);
        __builtin_amdgcn_s_setprio(0);
        BAR;

        // ---- p4: B ks1 qn1 (2 reads); stage A-kh1(T+2); vmcnt checkpoint ----
#pragma unroll
        for (int n = 0; n < 2; n++)
            b1[n] = *(const bf16x8*)(B1 + (wn * 64 + 32 + n * 16) * 64 + fo);
        if (T < 14) STA(2 * (T + 2) + 1);
        BAR;
        LGKM0;
        __builtin_amdgcn_s_setprio(1);
#pragma unroll
        for (int qm = 0; qm < 2; qm++)
#pragma unroll
            for (int m = 0; m < 4; m++)
#pragma unroll
                for (int n = 0; n < 2; n++)
                    acc[qm * 4 + m][2 + n] = MFMA(af[qm][m], b1[n], acc[qm * 4 + m][2 + n]);
        __builtin_amdgcn_s_setprio(0);
        if (T < 14) {
            VMCNT(6);  // all of tile T+1 guaranteed; 3 halves of T+2 in flight
        } else if (T == 14) {
            VMCNT(0);  // drain last half (B-kh1(15), issued 3 phases ago)
        }
        BAR;
    }
#undef STA
#undef STB

    int row0 = bm * 256 + wm * 128;
    int col0 = bn * 256 + wn * 64;
    if (OUT_BF16) {
        u16* C = (u16*)Cv;
#pragma unroll
        for (int qm = 0; qm < 2; qm++)
#pragma unroll
            for (int m = 0; m < 4; m++)
#pragma unroll
                for (int qn = 0; qn < 2; qn++)
#pragma unroll
                    for (int n = 0; n < 2; n++)
#pragma unroll
                        for (int r = 0; r < 4; r++) {
                            size_t rr = (size_t)(row0 + qm * 64 + m * 16 + g * 4 + r);
                            int cc = col0 + qn * 32 + n * 16 + lr;
                            C[rr * (size_t)ldc + cc] = f2b(acc[qm * 4 + m][qn * 2 + n][r]);
                        }
    } else {
        float* C = (float*)Cv;
#pragma unroll
        for (int qm = 0; qm < 2; qm++)
#pragma unroll
            for (int m = 0; m < 4; m++)
#pragma unroll
                for (int qn = 0; qn < 2; qn++)
#pragma unroll
                    for (int n = 0; n < 2; n++)
#pragma unroll
                        for (int r = 0; r < 4; r++) {
                            size_t rr = (size_t)(row0 + qm * 64 + m * 16 + g * 4 + r);
                            int cc = col0 + qn * 32 + n * 16 + lr;
                            float o = acc[qm * 4 + m][qn * 2 + n][r];
                            if (RESID) o += b2f(resid[rr * 1024 + cc]);
                            C[rr * (size_t)ldc + cc] = o;
                        }
    }
}

// ---------------------------------------------------------------------------
// Attention: one block per (b, head-group-of-4); wave w handles head hg*4+w.
// ---------------------------------------------------------------------------
__global__ __launch_bounds__(256) void attn_kernel(u16* __restrict__ qkv) {
    __shared__ u16 sq[32][264];
    __shared__ u16 sk[32][264];
    __shared__ u16 svt[256][40];
    __shared__ u16 sp[4][32][40];

    int t = threadIdx.x;
    int b = blockIdx.x >> 2, hg = blockIdx.x & 3;
    u16* base = qkv + (size_t)b * 28 * 3072 + hg * 256;

    {
        int rhalf = t >> 7;
        int c2 = (t & 127) * 2;
        for (int it = 0; it < 14; ++it) {
            int row = it * 2 + rhalf;
            const u16* src = base + (size_t)row * 3072;
            unsigned int qv = *(const unsigned int*)(src + c2);
            *(unsigned int*)&sq[row][c2] = qv;
            unsigned int kv = *(const unsigned int*)(src + 1024 + c2);
            *(unsigned int*)&sk[row][c2] = kv;
            unsigned int vv = *(const unsigned int*)(src + 2048 + c2);
            svt[c2][row] = (u16)(vv & 0xffffu);
            svt[c2 + 1][row] = (u16)(vv >> 16);
        }
#pragma unroll
        for (int r = 28; r < 32; ++r) {
            sq[r][t] = 0;
            sk[r][t] = 0;
        }
#pragma unroll
        for (int j = 28; j < 32; ++j) svt[t][j] = 0;
    }
    __syncthreads();

    int w = t >> 6, l = t & 63, g = l >> 4, lr = l & 15;
    int head = hg * 4 + w;

    f32x4 acc[2][2];
#pragma unroll
    for (int a = 0; a < 2; a++)
#pragma unroll
        for (int c = 0; c < 2; c++) acc[a][c] = {0.f, 0.f, 0.f, 0.f};
#pragma unroll
    for (int c = 0; c < 2; c++) {
        int d0 = w * 64 + c * 32 + g * 8;
        bf16x8 a0 = *(const bf16x8*)&sq[lr][d0];
        bf16x8 a1 = *(const bf16x8*)&sq[16 + lr][d0];
        bf16x8 b0 = *(const bf16x8*)&sk[lr][d0];
        bf16x8 b1 = *(const bf16x8*)&sk[16 + lr][d0];
        acc[0][0] = MFMA(a0, b0, acc[0][0]);
        acc[0][1] = MFMA(a0, b1, acc[0][1]);
        acc[1][0] = MFMA(a1, b0, acc[1][0]);
        acc[1][1] = MFMA(a1, b1, acc[1][1]);
    }

    float slope = exp2f(-0.5f * (float)(head + 1));
    int j0 = lr, j1 = 16 + lr;
    int j0m = j0 % 14, j0d = j0 / 14;
    int j1m = j1 % 14, j1d = j1 / 14;
#pragma unroll
    for (int it = 0; it < 2; ++it) {
#pragma unroll
        for (int r = 0; r < 4; ++r) {
            int i = it * 16 + g * 4 + r;
            int im = i % 14, id = i / 14;
            float s0 = acc[it][0][r] + slope * (float)(iabs(im - j0m) + iabs(id - j0d));
            float s1 = (j1 < 28)
                           ? acc[it][1][r] + slope * (float)(iabs(im - j1m) + iabs(id - j1d))
                           : -1e30f;
            float mx = fmaxf(s0, s1);
#pragma unroll
            for (int off = 1; off < 16; off <<= 1) mx = fmaxf(mx, __shfl_xor(mx, off));
            float e0 = __expf(s0 - mx), e1 = __expf(s1 - mx);
            float sm = e0 + e1;
#pragma unroll
            for (int off = 1; off < 16; off <<= 1) sm += __shfl_xor(sm, off);
            float inv = 1.f / sm;
            sp[w][i][lr] = f2b(e0 * inv);
            sp[w][i][16 + lr] = f2b(e1 * inv);
        }
    }
    __syncthreads();

    bf16x8 pa0 = *(const bf16x8*)&sp[w][lr][g * 8];
    bf16x8 pa1 = *(const bf16x8*)&sp[w][16 + lr][g * 8];
    f32x4 o[2][4];
#pragma unroll
    for (int a = 0; a < 2; a++)
#pragma unroll
        for (int d = 0; d < 4; d++) o[a][d] = {0.f, 0.f, 0.f, 0.f};
#pragma unroll
    for (int dt = 0; dt < 4; ++dt) {
        bf16x8 bv = *(const bf16x8*)&svt[w * 64 + dt * 16 + lr][g * 8];
        o[0][dt] = MFMA(pa0, bv, o[0][dt]);
        o[1][dt] = MFMA(pa1, bv, o[1][dt]);
    }
#pragma unroll
    for (int it = 0; it < 2; ++it)
#pragma unroll
        for (int dt = 0; dt < 4; ++dt)
#pragma unroll
            for (int r = 0; r < 4; ++r) {
                int i = it * 16 + g * 4 + r;
                if (i < 28) {
                    size_t off = (size_t)(b * 28 + i) * 3072 + hg * 256 + w * 64 + dt * 16 + lr;
                    qkv[off] = f2b(o[it][dt][r]);
                }
            }
}

// ---------------------------------------------------------------------------
extern "C" void kernel_launch(void* const* d_in, const int* in_sizes, int n_in,
                              void* d_out, int out_size, void* d_ws, size_t ws_size,
                              hipStream_t stream) {
    (void)in_sizes; (void)n_in; (void)out_size; (void)ws_size;
    const float* hidden = (const float*)d_in[0];
    const float* wq = (const float*)d_in[1];
    const float* wk = (const float*)d_in[2];
    const float* wv = (const float*)d_in[3];
    const float* wo = (const float*)d_in[4];
    const float* gamma = (const float*)d_in[5];
    const float* beta = (const float*)d_in[6];
    float* out = (float*)d_out;

    char* ws = (char*)d_ws;
    u16* h = (u16*)ws;                                          // 117,440,512 B
    u16* qkv = (u16*)(ws + 117440512);                          // 352,321,536 B
    u16* wqkvt = (u16*)(ws + 117440512 + 352321536);            //   6,291,456 B
    u16* wot = (u16*)(ws + 117440512 + 352321536 + 6291456);    //   2,097,152 B

    wconv_kernel<<<dim3(32, 32, 4), 256, 0, stream>>>(wq, wk, wv, wo, wqkvt, wot);
    ln_kernel<<<14336, 256, 0, stream>>>(hidden, gamma, beta, h);
    gemm8<1, 0><<<224 * 12, 512, 0, stream>>>(h, wqkvt, qkv, nullptr, 1024, 3072);
    attn_kernel<<<8192, 256, 0, stream>>>(qkv);
    gemm8<0, 1><<<224 * 4, 512, 0, stream>>>(qkv, wot, out, h, 3072, 1024);
}